// Round 1
// baseline (119.926 us; speedup 1.0000x reference)
//
#include <hip/hip_runtime.h>

// dqn MLP: 8 -> 5 -> 5 -> 5 -> 5 -> 5 -> 4, fp32.
// layer0: linear only; layers 1-4: linear+relu; layer5: linear+relu.
// BATCH = 2,097,152 rows. Memory-bound streaming kernel:
// one thread per row, float4 in (x2), float4 out, weights via uniform
// (scalar) loads.

#define IN_DIM 8
#define HID 5
#define OUT_DIM 4

__global__ __launch_bounds__(256) void dqn_mlp_kernel(
    const float* __restrict__ x,
    const float* __restrict__ W0, const float* __restrict__ b0,
    const float* __restrict__ W1, const float* __restrict__ b1,
    const float* __restrict__ W2, const float* __restrict__ b2,
    const float* __restrict__ W3, const float* __restrict__ b3,
    const float* __restrict__ W4, const float* __restrict__ b4,
    const float* __restrict__ W5, const float* __restrict__ b5,
    float* __restrict__ out, int batch)
{
    int i = blockIdx.x * blockDim.x + threadIdx.x;
    if (i >= batch) return;

    // Load the 8-float input row as two float4 (32B/lane, coalesced).
    const float4* xv = reinterpret_cast<const float4*>(x);
    float4 xa = xv[2 * i];
    float4 xb = xv[2 * i + 1];
    float xin[IN_DIM] = {xa.x, xa.y, xa.z, xa.w, xb.x, xb.y, xb.z, xb.w};

    float h[HID];
    // input layer: linear only (no relu)
    #pragma unroll
    for (int j = 0; j < HID; ++j) {
        float s = b0[j];
        #pragma unroll
        for (int k = 0; k < IN_DIM; ++k) s = fmaf(xin[k], W0[j * IN_DIM + k], s);
        h[j] = s;
    }

    // hidden layers 1..4: linear + relu
    const float* __restrict__ Ws[4] = {W1, W2, W3, W4};
    const float* __restrict__ bs[4] = {b1, b2, b3, b4};
    #pragma unroll
    for (int l = 0; l < 4; ++l) {
        float g[HID];
        #pragma unroll
        for (int j = 0; j < HID; ++j) {
            float s = bs[l][j];
            #pragma unroll
            for (int k = 0; k < HID; ++k) s = fmaf(h[k], Ws[l][j * HID + k], s);
            g[j] = fmaxf(s, 0.0f);
        }
        #pragma unroll
        for (int j = 0; j < HID; ++j) h[j] = g[j];
    }

    // output layer: linear + relu
    float ov[OUT_DIM];
    #pragma unroll
    for (int j = 0; j < OUT_DIM; ++j) {
        float s = b5[j];
        #pragma unroll
        for (int k = 0; k < HID; ++k) s = fmaf(h[k], W5[j * HID + k], s);
        ov[j] = fmaxf(s, 0.0f);
    }

    reinterpret_cast<float4*>(out)[i] = make_float4(ov[0], ov[1], ov[2], ov[3]);
}

extern "C" void kernel_launch(void* const* d_in, const int* in_sizes, int n_in,
                              void* d_out, int out_size, void* d_ws, size_t ws_size,
                              hipStream_t stream) {
    const float* x  = (const float*)d_in[0];
    const float* W0 = (const float*)d_in[1];
    const float* b0 = (const float*)d_in[2];
    const float* W1 = (const float*)d_in[3];
    const float* b1 = (const float*)d_in[4];
    const float* W2 = (const float*)d_in[5];
    const float* b2 = (const float*)d_in[6];
    const float* W3 = (const float*)d_in[7];
    const float* b3 = (const float*)d_in[8];
    const float* W4 = (const float*)d_in[9];
    const float* b4 = (const float*)d_in[10];
    const float* W5 = (const float*)d_in[11];
    const float* b5 = (const float*)d_in[12];
    float* out = (float*)d_out;

    int batch = in_sizes[0] / IN_DIM;
    int block = 256;
    int grid = (batch + block - 1) / block;
    dqn_mlp_kernel<<<grid, block, 0, stream>>>(
        x, W0, b0, W1, b1, W2, b2, W3, b3, W4, b4, W5, b5, out, batch);
}